// Round 1
// baseline (18603.593 us; speedup 1.0000x reference)
//
#include <hip/hip_runtime.h>
#include <math.h>

// ComplexPolarTransformerBeta: fused single-kernel fp32 implementation.
// One block per molecule (B=1024), 512 threads: thread t owns row r=t>>2,
// column-quarter qd=t&3 (32 floats) of every [128,128] activation.
// LDS: one 64KB buffer S, time-multiplexed. XOR swizzle on float4 slots
// breaks the 512B-row-stride bank alignment.

#define NROW 128
#define HDIM 128

__device__ __forceinline__ int swslot(int row, int f4) {
  return (f4 ^ (row & 31) ^ ((row >> 5) << 3)) & 31;
}

// out[32] (cols colbase..colbase+31) = S[r,:] @ W[:,cols] (+bias if !ACCUM)
template<bool ACCUM>
__device__ __forceinline__ void rowgemm(const float* __restrict__ S, int r,
                                        const float* __restrict__ W,
                                        int colbase,
                                        const float* __restrict__ bias,
                                        float out[32]) {
  const float4* S4 = (const float4*)S;
  if (!ACCUM) {
    #pragma unroll
    for (int i = 0; i < 8; ++i) {
      float4 b4 = *(const float4*)(bias + colbase + 4 * i);
      out[4*i+0] = b4.x; out[4*i+1] = b4.y; out[4*i+2] = b4.z; out[4*i+3] = b4.w;
    }
  }
  #pragma unroll 4
  for (int d4 = 0; d4 < 32; ++d4) {
    float4 a = S4[r * 32 + swslot(r, d4)];
    #pragma unroll
    for (int dd = 0; dd < 4; ++dd) {
      float av = (dd == 0) ? a.x : ((dd == 1) ? a.y : ((dd == 2) ? a.z : a.w));
      const float* Wrow = W + (size_t)(d4 * 4 + dd) * HDIM + colbase;
      #pragma unroll
      for (int i = 0; i < 8; ++i) {
        float4 w4 = *(const float4*)(Wrow + 4 * i);
        out[4*i+0] += av * w4.x; out[4*i+1] += av * w4.y;
        out[4*i+2] += av * w4.z; out[4*i+3] += av * w4.w;
      }
    }
  }
}

__device__ __forceinline__ void stage32(float* __restrict__ S, int r, int qd,
                                        const float v[32]) {
  float4* S4 = (float4*)S;
  #pragma unroll
  for (int i = 0; i < 8; ++i) {
    S4[r * 32 + swslot(r, qd * 8 + i)] =
        make_float4(v[4*i], v[4*i+1], v[4*i+2], v[4*i+3]);
  }
}

__global__ __launch_bounds__(512)
void cpt_kernel(const float* __restrict__ atom_types,
                const float* __restrict__ coords,
                const int*   __restrict__ edge_index,
                const float* __restrict__ edge_attr,
                const float* __restrict__ emb_Wm, const float* __restrict__ emb_bm,
                const float* __restrict__ emb_Wp, const float* __restrict__ emb_bp,
                const float* __restrict__ Wq,  const float* __restrict__ bq,
                const float* __restrict__ Wk,  const float* __restrict__ bk,
                const float* __restrict__ Wvm, const float* __restrict__ bvm,
                const float* __restrict__ Wvp, const float* __restrict__ bvp,
                const float* __restrict__ We,  const float* __restrict__ be,
                const float* __restrict__ dist_scale,
                const float* __restrict__ ln_g, const float* __restrict__ ln_b,
                const float* __restrict__ rp_W, const float* __restrict__ rp_b,
                const float* __restrict__ h1_W, const float* __restrict__ h1_b,
                const float* __restrict__ h2_W, const float* __restrict__ h2_b,
                float* __restrict__ out)
{
  __shared__ float S[NROW * HDIM];
  const int t = threadIdx.x;
  const int b = blockIdx.x;
  const int r = t >> 2;
  const int qd = t & 3;
  const int colbase = qd * 32;

  float mag[32], ph[32];

  // ---------------- embedding ----------------
  {
    float x[19];
    const float* at = atom_types + ((size_t)b * NROW + r) * 16;
    #pragma unroll
    for (int i = 0; i < 4; ++i) {
      float4 v = *(const float4*)(at + 4 * i);
      x[4*i+0] = v.x; x[4*i+1] = v.y; x[4*i+2] = v.z; x[4*i+3] = v.w;
    }
    const float* cs = coords + ((size_t)b * NROW + r) * 3;
    x[16] = cs[0]; x[17] = cs[1]; x[18] = cs[2];
    #pragma unroll
    for (int i = 0; i < 8; ++i) {
      float4 bm4 = *(const float4*)(emb_bm + colbase + 4 * i);
      float4 bp4 = *(const float4*)(emb_bp + colbase + 4 * i);
      mag[4*i+0] = bm4.x; mag[4*i+1] = bm4.y; mag[4*i+2] = bm4.z; mag[4*i+3] = bm4.w;
      ph[4*i+0]  = bp4.x; ph[4*i+1]  = bp4.y; ph[4*i+2]  = bp4.z; ph[4*i+3]  = bp4.w;
    }
    for (int d = 0; d < 19; ++d) {
      float xv = x[d];
      const float* wm = emb_Wm + d * HDIM + colbase;
      const float* wp = emb_Wp + d * HDIM + colbase;
      #pragma unroll
      for (int i = 0; i < 8; ++i) {
        float4 wm4 = *(const float4*)(wm + 4 * i);
        float4 wp4 = *(const float4*)(wp + 4 * i);
        mag[4*i+0] += xv * wm4.x; mag[4*i+1] += xv * wm4.y;
        mag[4*i+2] += xv * wm4.z; mag[4*i+3] += xv * wm4.w;
        ph[4*i+0]  += xv * wp4.x; ph[4*i+1]  += xv * wp4.y;
        ph[4*i+2]  += xv * wp4.z; ph[4*i+3]  += xv * wp4.w;
      }
    }
  }

  const float scale = 0.08838834764831845f;  // 1/sqrt(128)

  // ---------------- layers ----------------
  for (int l = 0; l < 4; ++l) {
    const float* Wq_l  = Wq  + (size_t)l * HDIM * HDIM;
    const float* Wk_l  = Wk  + (size_t)l * HDIM * HDIM;
    const float* Wvm_l = Wvm + (size_t)l * HDIM * HDIM;
    const float* Wvp_l = Wvp + (size_t)l * HDIM * HDIM;
    const float* bq_l  = bq  + l * HDIM;
    const float* bk_l  = bk  + l * HDIM;
    const float* bvm_l = bvm + l * HDIM;
    const float* bvp_l = bvp + l * HDIM;

    __syncthreads();                       // previous readers of S done
    {                                      // zero S
      float4 z = make_float4(0.f, 0.f, 0.f, 0.f);
      float4* S4 = (float4*)S;
      #pragma unroll
      for (int i = 0; i < 8; ++i) S4[i * 512 + t] = z;
    }
    __syncthreads();
    {                                      // edge-bias scatter into S (swizzled)
      float We0 = We[l*4+0], We1 = We[l*4+1], We2 = We[l*4+2], We3 = We[l*4+3];
      float bel = be[l];
      float dsl = dist_scale[l];
      #pragma unroll
      for (int eo = 0; eo < 2; ++eo) {
        int e = t + eo * 512;
        int ei0 = edge_index[(size_t)b * 2048 + e];
        int ei1 = edge_index[(size_t)b * 2048 + 1024 + e];
        float4 ea = *(const float4*)(edge_attr + ((size_t)b * 1024 + e) * 4);
        float bval = ea.x*We0 + ea.y*We1 + ea.z*We2 + ea.w*We3 + bel + dsl*ea.x;
        int idx = ei0 * HDIM + (swslot(ei0, ei1 >> 2) << 2) + (ei1 & 3);
        atomicAdd(&S[idx], bval);
      }
    }
    __syncthreads();
    float sb[32];                          // bias slice -> scores -> attn
    {
      const float4* S4 = (const float4*)S;
      #pragma unroll
      for (int i = 0; i < 8; ++i) {
        float4 v = S4[r * 32 + swslot(r, qd * 8 + i)];
        sb[4*i+0] = v.x; sb[4*i+1] = v.y; sb[4*i+2] = v.z; sb[4*i+3] = v.w;
      }
    }
    // own-row only from here until next barrier: no sync needed
    stage32(S, r, qd, mag);
    float A[32], Bv[32];
    rowgemm<false>(S, r, Wq_l, colbase, bq_l, A);    // q
    rowgemm<false>(S, r, Wk_l, colbase, bk_l, Bv);   // k
    __syncthreads();                       // all mag reads done
    stage32(S, r, qd, Bv);                 // stage k
    __syncthreads();
    {                                      // scores: sb += scale * q . k^T
      const float4* S4 = (const float4*)S;
      #pragma unroll 1
      for (int jb = 0; jb < 4; ++jb) {
        float p[32];
        #pragma unroll 2
        for (int jj = 0; jj < 32; ++jj) {
          int j = jb * 32 + jj;
          float4 acc = make_float4(0.f, 0.f, 0.f, 0.f);
          #pragma unroll
          for (int i = 0; i < 8; ++i) {
            float4 kv = S4[j * 32 + swslot(j, qd * 8 + i)];
            acc.x += A[4*i+0] * kv.x;
            acc.y += A[4*i+1] * kv.y;
            acc.z += A[4*i+2] * kv.z;
            acc.w += A[4*i+3] * kv.w;
          }
          p[jj] = (acc.x + acc.y) + (acc.z + acc.w);
        }
        #pragma unroll
        for (int jj = 0; jj < 32; ++jj) {
          p[jj] += __shfl_xor(p[jj], 1);
          p[jj] += __shfl_xor(p[jj], 2);
        }
        if (qd == jb) {
          #pragma unroll
          for (int jj = 0; jj < 32; ++jj) sb[jj] += scale * p[jj];
        }
      }
    }
    {                                      // softmax over the row
      float m = sb[0];
      #pragma unroll
      for (int i = 1; i < 32; ++i) m = fmaxf(m, sb[i]);
      m = fmaxf(m, __shfl_xor(m, 1));
      m = fmaxf(m, __shfl_xor(m, 2));
      float s = 0.f;
      #pragma unroll
      for (int i = 0; i < 32; ++i) { sb[i] = __expf(sb[i] - m); s += sb[i]; }
      s += __shfl_xor(s, 1);
      s += __shfl_xor(s, 2);
      float inv = 1.f / s;
      #pragma unroll
      for (int i = 0; i < 32; ++i) sb[i] *= inv;
    }
    __syncthreads();                       // scores readers done with k
    stage32(S, r, qd, mag);                // re-stage mag (own row)
    rowgemm<false>(S, r, Wvm_l, colbase, bvm_l, A);  // vm
    stage32(S, r, qd, A);                  // stage vm (own row)
    __syncthreads();                       // all vm staged
    {                                      // new_mag = attn @ vm
      const float4* S4 = (const float4*)S;
      #pragma unroll 1
      for (int cb = 0; cb < 4; ++cb) {
        float p[32];
        #pragma unroll
        for (int i = 0; i < 32; ++i) p[i] = 0.f;
        #pragma unroll 2
        for (int jj = 0; jj < 32; ++jj) {
          int j = qd * 32 + jj;
          float a = sb[jj];
          #pragma unroll
          for (int i = 0; i < 8; ++i) {
            float4 v = S4[j * 32 + swslot(j, cb * 8 + i)];
            p[4*i+0] += a * v.x; p[4*i+1] += a * v.y;
            p[4*i+2] += a * v.z; p[4*i+3] += a * v.w;
          }
        }
        #pragma unroll
        for (int i = 0; i < 32; ++i) {
          p[i] += __shfl_xor(p[i], 1);
          p[i] += __shfl_xor(p[i], 2);
        }
        if (qd == cb) {
          #pragma unroll
          for (int i = 0; i < 32; ++i) A[i] = p[i];
        }
      }
    }
    {                                      // residual + LayerNorm -> mag
      float sum = 0.f, sq = 0.f;
      #pragma unroll
      for (int i = 0; i < 32; ++i) {
        float v = A[i] + mag[i];
        A[i] = v; sum += v; sq += v * v;
      }
      sum += __shfl_xor(sum, 1); sum += __shfl_xor(sum, 2);
      sq  += __shfl_xor(sq, 1);  sq  += __shfl_xor(sq, 2);
      float mu  = sum * (1.f / 128.f);
      float var = sq * (1.f / 128.f) - mu * mu;
      float inv = 1.f / sqrtf(var + 1e-5f);
      const float* g  = ln_g + l * HDIM + colbase;
      const float* bb = ln_b + l * HDIM + colbase;
      #pragma unroll
      for (int i = 0; i < 32; ++i)
        mag[i] = g[i] * ((A[i] - mu) * inv) + bb[i];
    }
    __syncthreads();                       // nm readers done with vm
    stage32(S, r, qd, ph);                 // stage ph (own row)
    rowgemm<false>(S, r, Wvp_l, colbase, bvp_l, A);  // vp
    stage32(S, r, qd, A);                  // stage vp (own row)
    __syncthreads();
    {                                      // new_ph = attn @ vp + ph
      const float4* S4 = (const float4*)S;
      #pragma unroll 1
      for (int cb = 0; cb < 4; ++cb) {
        float p[32];
        #pragma unroll
        for (int i = 0; i < 32; ++i) p[i] = 0.f;
        #pragma unroll 2
        for (int jj = 0; jj < 32; ++jj) {
          int j = qd * 32 + jj;
          float a = sb[jj];
          #pragma unroll
          for (int i = 0; i < 8; ++i) {
            float4 v = S4[j * 32 + swslot(j, cb * 8 + i)];
            p[4*i+0] += a * v.x; p[4*i+1] += a * v.y;
            p[4*i+2] += a * v.z; p[4*i+3] += a * v.w;
          }
        }
        #pragma unroll
        for (int i = 0; i < 32; ++i) {
          p[i] += __shfl_xor(p[i], 1);
          p[i] += __shfl_xor(p[i], 2);
        }
        if (qd == cb) {
          #pragma unroll
          for (int i = 0; i < 32; ++i) ph[i] += p[i];
        }
      }
    }
  } // layers

  // ---------------- real/imag -> RealProjection ----------------
  #pragma unroll
  for (int i = 0; i < 32; ++i) {
    float s_, c_;
    __sincosf(ph[i], &s_, &c_);
    float re = mag[i] * c_;
    float im = mag[i] * s_;
    mag[i] = re; ph[i] = im;
  }
  __syncthreads();                         // np readers done (last layer)
  float ar[32];
  stage32(S, r, qd, mag);                  // real
  rowgemm<false>(S, r, rp_W, colbase, rp_b, ar);
  stage32(S, r, qd, ph);                   // imag (own row, safe)
  rowgemm<true>(S, r, rp_W + 128 * HDIM, colbase, nullptr, ar);

  // ---------------- pooling + head ----------------
  {                                        // plain-layout stage of atom_repr
    float4* S4 = (float4*)S;
    #pragma unroll
    for (int i = 0; i < 8; ++i)
      S4[r * 32 + qd * 8 + i] = make_float4(ar[4*i], ar[4*i+1], ar[4*i+2], ar[4*i+3]);
  }
  __syncthreads();
  {
    int c = t & 127, g = t >> 7;
    float psum = 0.f;
    #pragma unroll 8
    for (int i = 0; i < 32; ++i) psum += S[(g * 32 + i) * HDIM + c];
    __syncthreads();
    S[g * HDIM + c] = psum;
    __syncthreads();
    if (t < 128) {
      float cs = S[t] + S[128 + t] + S[256 + t] + S[384 + t];
      S[t] = cs;                           // colsum (sum-pool); mean = cs/128
    }
    __syncthreads();
    if (t < 128) {
      float acc = h1_b[t];
      for (int i = 0; i < 128; ++i) {
        float cs = S[i];
        acc += cs * (h1_W[(size_t)i * HDIM + t] * (1.f / 128.f) +
                     h1_W[(size_t)(128 + i) * HDIM + t]);
      }
      float hv = acc / (1.f + __expf(-acc));   // SiLU
      S[128 + t] = hv * h2_W[t];
    }
    __syncthreads();
    if (t < 64) {
      float s2 = S[128 + t] + S[192 + t];
      #pragma unroll
      for (int off = 32; off >= 1; off >>= 1) s2 += __shfl_xor(s2, off);
      if (t == 0) out[b] = s2 + h2_b[0];
    }
  }
}

extern "C" void kernel_launch(void* const* d_in, const int* in_sizes, int n_in,
                              void* d_out, int out_size, void* d_ws, size_t ws_size,
                              hipStream_t stream) {
  const float* atom_types = (const float*)d_in[0];
  const float* coords     = (const float*)d_in[1];
  const int*   edge_index = (const int*)  d_in[2];
  const float* edge_attr  = (const float*)d_in[3];
  const float* emb_Wm = (const float*)d_in[4];
  const float* emb_bm = (const float*)d_in[5];
  const float* emb_Wp = (const float*)d_in[6];
  const float* emb_bp = (const float*)d_in[7];
  const float* Wq  = (const float*)d_in[8];
  const float* bq  = (const float*)d_in[9];
  const float* Wk  = (const float*)d_in[10];
  const float* bk  = (const float*)d_in[11];
  const float* Wvm = (const float*)d_in[12];
  const float* bvm = (const float*)d_in[13];
  const float* Wvp = (const float*)d_in[14];
  const float* bvp = (const float*)d_in[15];
  const float* We  = (const float*)d_in[16];
  const float* be  = (const float*)d_in[17];
  const float* dist_scale = (const float*)d_in[18];
  const float* ln_g = (const float*)d_in[19];
  const float* ln_b = (const float*)d_in[20];
  const float* rp_W = (const float*)d_in[21];
  const float* rp_b = (const float*)d_in[22];
  const float* h1_W = (const float*)d_in[23];
  const float* h1_b = (const float*)d_in[24];
  const float* h2_W = (const float*)d_in[25];
  const float* h2_b = (const float*)d_in[26];
  float* out = (float*)d_out;

  hipLaunchKernelGGL(cpt_kernel, dim3(1024), dim3(512), 0, stream,
                     atom_types, coords, edge_index, edge_attr,
                     emb_Wm, emb_bm, emb_Wp, emb_bp,
                     Wq, bq, Wk, bk, Wvm, bvm, Wvp, bvp,
                     We, be, dist_scale, ln_g, ln_b,
                     rp_W, rp_b, h1_W, h1_b, h2_W, h2_b,
                     out);
}

// Round 2
// 2072.338 us; speedup vs baseline: 8.9771x; 8.9771x over previous
//
#include <hip/hip_runtime.h>
#include <math.h>

// ComplexPolarTransformerBeta — round 2.
// One block per molecule (B=1024), 512 threads. Register-tiled 4x8:
//   thread t: rt = t>>4 (rows 4rt..4rt+3), ct = t&15 (cols 8ct..8ct+7).
// Persistent per-thread state: magT[32], phT[32] (tile layout).
// Two LDS buffers SA/SB (128 rows x 33 float4, ~66KB each; gfx950 has 160KB LDS).
// All matrix ops are tiled GEMMs through LDS; __launch_bounds__(512,2) -> 256 VGPR cap.

#define RS 33  // row stride in float4 units (128 floats data + 4 pad)

__device__ __forceinline__ int aidx(int row, int cf) {
  // cf = column/4 chunk (0..31). Permute so hot patterns are <=2-way banked.
  int slot = ((cf >> 1) | ((cf & 1) << 4));
  return row * RS + ((slot + (row >> 3)) & 31);
}

__device__ __forceinline__ void tstage(float4* S4, int r0, int ct, const float v[32]) {
  #pragma unroll
  for (int i = 0; i < 4; ++i) {
    S4[aidx(r0 + i, 2 * ct)]     = make_float4(v[i*8+0], v[i*8+1], v[i*8+2], v[i*8+3]);
    S4[aidx(r0 + i, 2 * ct + 1)] = make_float4(v[i*8+4], v[i*8+5], v[i*8+6], v[i*8+7]);
  }
}

__device__ __forceinline__ void tread(const float4* S4, int r0, int ct, float v[32]) {
  #pragma unroll
  for (int i = 0; i < 4; ++i) {
    float4 a = S4[aidx(r0 + i, 2 * ct)];
    float4 c = S4[aidx(r0 + i, 2 * ct + 1)];
    v[i*8+0] = a.x; v[i*8+1] = a.y; v[i*8+2] = a.z; v[i*8+3] = a.w;
    v[i*8+4] = c.x; v[i*8+5] = c.y; v[i*8+6] = c.z; v[i*8+7] = c.w;
  }
}

// out(4x8) = A(LDS rows r0..r0+3) @ W[128x128] (+ bias)
template<bool ACCUM>
__device__ __forceinline__ void wgemm(const float4* __restrict__ A4, int r0, int cb,
                                      const float* __restrict__ W,
                                      const float* __restrict__ bias, float out[32]) {
  if (!ACCUM) {
    float4 b0 = *(const float4*)(bias + cb);
    float4 b1 = *(const float4*)(bias + cb + 4);
    #pragma unroll
    for (int i = 0; i < 4; ++i) {
      out[i*8+0] = b0.x; out[i*8+1] = b0.y; out[i*8+2] = b0.z; out[i*8+3] = b0.w;
      out[i*8+4] = b1.x; out[i*8+5] = b1.y; out[i*8+6] = b1.z; out[i*8+7] = b1.w;
    }
  }
  #pragma unroll 2
  for (int k4 = 0; k4 < 32; ++k4) {
    float4 a0 = A4[aidx(r0 + 0, k4)];
    float4 a1 = A4[aidx(r0 + 1, k4)];
    float4 a2 = A4[aidx(r0 + 2, k4)];
    float4 a3 = A4[aidx(r0 + 3, k4)];
    #pragma unroll
    for (int kk = 0; kk < 4; ++kk) {
      const float* wr = W + (size_t)(k4 * 4 + kk) * 128 + cb;
      float4 w0 = *(const float4*)wr;
      float4 w1 = *(const float4*)(wr + 4);
      float av0 = kk==0?a0.x:kk==1?a0.y:kk==2?a0.z:a0.w;
      float av1 = kk==0?a1.x:kk==1?a1.y:kk==2?a1.z:a1.w;
      float av2 = kk==0?a2.x:kk==1?a2.y:kk==2?a2.z:a2.w;
      float av3 = kk==0?a3.x:kk==1?a3.y:kk==2?a3.z:a3.w;
      out[0]  += av0*w0.x; out[1]  += av0*w0.y; out[2]  += av0*w0.z; out[3]  += av0*w0.w;
      out[4]  += av0*w1.x; out[5]  += av0*w1.y; out[6]  += av0*w1.z; out[7]  += av0*w1.w;
      out[8]  += av1*w0.x; out[9]  += av1*w0.y; out[10] += av1*w0.z; out[11] += av1*w0.w;
      out[12] += av1*w1.x; out[13] += av1*w1.y; out[14] += av1*w1.z; out[15] += av1*w1.w;
      out[16] += av2*w0.x; out[17] += av2*w0.y; out[18] += av2*w0.z; out[19] += av2*w0.w;
      out[20] += av2*w1.x; out[21] += av2*w1.y; out[22] += av2*w1.z; out[23] += av2*w1.w;
      out[24] += av3*w0.x; out[25] += av3*w0.y; out[26] += av3*w0.z; out[27] += av3*w0.w;
      out[28] += av3*w1.x; out[29] += av3*w1.y; out[30] += av3*w1.z; out[31] += av3*w1.w;
    }
  }
}

// s(4x8) = Q(rows r0..+3) @ K(rows j0..+7)^T   (both in LDS, K-dim contiguous)
__device__ __forceinline__ void scoresf(const float4* __restrict__ Q4,
                                        const float4* __restrict__ K4,
                                        int r0, int j0, float s[32]) {
  #pragma unroll
  for (int i = 0; i < 32; ++i) s[i] = 0.f;
  #pragma unroll 1
  for (int k4 = 0; k4 < 32; ++k4) {
    float4 q0 = Q4[aidx(r0 + 0, k4)];
    float4 q1 = Q4[aidx(r0 + 1, k4)];
    float4 q2 = Q4[aidx(r0 + 2, k4)];
    float4 q3 = Q4[aidx(r0 + 3, k4)];
    #pragma unroll
    for (int j = 0; j < 8; ++j) {
      float4 kv = K4[aidx(j0 + j, k4)];
      s[0*8+j] += q0.x*kv.x + q0.y*kv.y + q0.z*kv.z + q0.w*kv.w;
      s[1*8+j] += q1.x*kv.x + q1.y*kv.y + q1.z*kv.z + q1.w*kv.w;
      s[2*8+j] += q2.x*kv.x + q2.y*kv.y + q2.z*kv.z + q2.w*kv.w;
      s[3*8+j] += q3.x*kv.x + q3.y*kv.y + q3.z*kv.z + q3.w*kv.w;
    }
  }
}

// o(4x8) = P(rows r0..+3) @ V (K = 128 rows of V, cols 8ct..8ct+7)
__device__ __forceinline__ void avgemm(const float4* __restrict__ P4,
                                       const float4* __restrict__ V4,
                                       int r0, int ct, float o[32]) {
  #pragma unroll
  for (int i = 0; i < 32; ++i) o[i] = 0.f;
  #pragma unroll 1
  for (int j4 = 0; j4 < 32; ++j4) {
    float4 p0 = P4[aidx(r0 + 0, j4)];
    float4 p1 = P4[aidx(r0 + 1, j4)];
    float4 p2 = P4[aidx(r0 + 2, j4)];
    float4 p3 = P4[aidx(r0 + 3, j4)];
    #pragma unroll
    for (int jj = 0; jj < 4; ++jj) {
      int j = j4 * 4 + jj;
      float4 v0 = V4[aidx(j, 2 * ct)];
      float4 v1 = V4[aidx(j, 2 * ct + 1)];
      float pa = jj==0?p0.x:jj==1?p0.y:jj==2?p0.z:p0.w;
      float pb = jj==0?p1.x:jj==1?p1.y:jj==2?p1.z:p1.w;
      float pc = jj==0?p2.x:jj==1?p2.y:jj==2?p2.z:p2.w;
      float pd = jj==0?p3.x:jj==1?p3.y:jj==2?p3.z:p3.w;
      o[0]  += pa*v0.x; o[1]  += pa*v0.y; o[2]  += pa*v0.z; o[3]  += pa*v0.w;
      o[4]  += pa*v1.x; o[5]  += pa*v1.y; o[6]  += pa*v1.z; o[7]  += pa*v1.w;
      o[8]  += pb*v0.x; o[9]  += pb*v0.y; o[10] += pb*v0.z; o[11] += pb*v0.w;
      o[12] += pb*v1.x; o[13] += pb*v1.y; o[14] += pb*v1.z; o[15] += pb*v1.w;
      o[16] += pc*v0.x; o[17] += pc*v0.y; o[18] += pc*v0.z; o[19] += pc*v0.w;
      o[20] += pc*v1.x; o[21] += pc*v1.y; o[22] += pc*v1.z; o[23] += pc*v1.w;
      o[24] += pd*v0.x; o[25] += pd*v0.y; o[26] += pd*v0.z; o[27] += pd*v0.w;
      o[28] += pd*v1.x; o[29] += pd*v1.y; o[30] += pd*v1.z; o[31] += pd*v1.w;
    }
  }
}

__global__ __launch_bounds__(512, 2)
void cpt_kernel(const float* __restrict__ atom_types,
                const float* __restrict__ coords,
                const int*   __restrict__ edge_index,
                const float* __restrict__ edge_attr,
                const float* __restrict__ emb_Wm, const float* __restrict__ emb_bm,
                const float* __restrict__ emb_Wp, const float* __restrict__ emb_bp,
                const float* __restrict__ Wq,  const float* __restrict__ bq,
                const float* __restrict__ Wk,  const float* __restrict__ bk,
                const float* __restrict__ Wvm, const float* __restrict__ bvm,
                const float* __restrict__ Wvp, const float* __restrict__ bvp,
                const float* __restrict__ We,  const float* __restrict__ be,
                const float* __restrict__ dist_scale,
                const float* __restrict__ ln_g, const float* __restrict__ ln_b,
                const float* __restrict__ rp_W, const float* __restrict__ rp_b,
                const float* __restrict__ h1_W, const float* __restrict__ h1_b,
                const float* __restrict__ h2_W, const float* __restrict__ h2_b,
                float* __restrict__ out)
{
  __shared__ float4 SA4[128 * RS];
  __shared__ float4 SB4[128 * RS];

  const int t = threadIdx.x;
  const int b = blockIdx.x;
  const int rt = t >> 4, ct = t & 15;
  const int r0 = rt * 4, cb = ct * 8;

  float magT[32], phT[32];

  // ---------------- embedding (tile layout) ----------------
  {
    float4 bm0 = *(const float4*)(emb_bm + cb);
    float4 bm1 = *(const float4*)(emb_bm + cb + 4);
    float4 bp0 = *(const float4*)(emb_bp + cb);
    float4 bp1 = *(const float4*)(emb_bp + cb + 4);
    #pragma unroll 1
    for (int i = 0; i < 4; ++i) {
      int row = r0 + i;
      float x[19];
      const float* at = atom_types + ((size_t)b * 128 + row) * 16;
      #pragma unroll
      for (int q = 0; q < 4; ++q) {
        float4 v = *(const float4*)(at + 4 * q);
        x[4*q+0] = v.x; x[4*q+1] = v.y; x[4*q+2] = v.z; x[4*q+3] = v.w;
      }
      const float* cs = coords + ((size_t)b * 128 + row) * 3;
      x[16] = cs[0]; x[17] = cs[1]; x[18] = cs[2];
      float m[8] = {bm0.x,bm0.y,bm0.z,bm0.w,bm1.x,bm1.y,bm1.z,bm1.w};
      float p[8] = {bp0.x,bp0.y,bp0.z,bp0.w,bp1.x,bp1.y,bp1.z,bp1.w};
      #pragma unroll 1
      for (int d = 0; d < 19; ++d) {
        float xv = x[d];
        const float* wm = emb_Wm + d * 128 + cb;
        const float* wp = emb_Wp + d * 128 + cb;
        float4 a0 = *(const float4*)wm, a1 = *(const float4*)(wm + 4);
        float4 c0 = *(const float4*)wp, c1 = *(const float4*)(wp + 4);
        m[0]+=xv*a0.x; m[1]+=xv*a0.y; m[2]+=xv*a0.z; m[3]+=xv*a0.w;
        m[4]+=xv*a1.x; m[5]+=xv*a1.y; m[6]+=xv*a1.z; m[7]+=xv*a1.w;
        p[0]+=xv*c0.x; p[1]+=xv*c0.y; p[2]+=xv*c0.z; p[3]+=xv*c0.w;
        p[4]+=xv*c1.x; p[5]+=xv*c1.y; p[6]+=xv*c1.z; p[7]+=xv*c1.w;
      }
      #pragma unroll
      for (int c = 0; c < 8; ++c) { magT[i*8+c] = m[c]; phT[i*8+c] = p[c]; }
    }
  }

  const float scale = 0.08838834764831845f;  // 1/sqrt(128)

  for (int l = 0; l < 4; ++l) {
    const float* Wq_l  = Wq  + (size_t)l * 16384;
    const float* Wk_l  = Wk  + (size_t)l * 16384;
    const float* Wvm_l = Wvm + (size_t)l * 16384;
    const float* Wvp_l = Wvp + (size_t)l * 16384;

    __syncthreads();                                   // prev layer's readers done
    {                                                  // zero SB (bias buffer)
      float4 z = make_float4(0.f, 0.f, 0.f, 0.f);
      #pragma unroll
      for (int k = 0; k < 9; ++k) {
        int idx = t + k * 512;
        if (idx < 128 * RS) SB4[idx] = z;
      }
    }
    tstage(SA4, r0, ct, magT);                         // mag -> SA
    __syncthreads();
    {                                                  // edge-bias scatter -> SB
      float We0 = We[l*4+0], We1 = We[l*4+1], We2 = We[l*4+2], We3 = We[l*4+3];
      float bel = be[l];
      float dsl = dist_scale[l];
      #pragma unroll
      for (int eo = 0; eo < 2; ++eo) {
        int e = t + eo * 512;
        int ei0 = edge_index[(size_t)b * 2048 + e];
        int ei1 = edge_index[(size_t)b * 2048 + 1024 + e];
        float4 ea = *(const float4*)(edge_attr + ((size_t)b * 1024 + e) * 4);
        float bval = ea.x*We0 + ea.y*We1 + ea.z*We2 + ea.w*We3 + bel + dsl*ea.x;
        int fi = aidx(ei0, ei1 >> 2) * 4 + (ei1 & 3);
        atomicAdd((float*)SB4 + fi, bval);
      }
    }
    __syncthreads();
    float bT[32];
    tread(SB4, r0, ct, bT);                            // bias tile -> regs
    float qT[32];
    wgemm<false>(SA4, r0, cb, Wq_l, bq + l * 128, qT); // q = mag@Wq
    __syncthreads();                                   // bias reads done
    tstage(SB4, r0, ct, qT);                           // q -> SB
    {
      float kT[32];
      wgemm<false>(SA4, r0, cb, Wk_l, bk + l * 128, kT);
      __syncthreads();                                 // SA reads + SB q-writes done
      tstage(SA4, r0, ct, kT);                         // k -> SA (over mag)
    }
    __syncthreads();
    float sT[32];
    scoresf(SB4, SA4, r0, cb, sT);                     // q @ k^T
    {                                                  // + bias, softmax per row
      float mx[4];
      #pragma unroll
      for (int i = 0; i < 4; ++i) {
        float m = -1e30f;
        #pragma unroll
        for (int c = 0; c < 8; ++c) {
          float v = bT[i*8+c] + scale * sT[i*8+c];
          sT[i*8+c] = v;
          m = fmaxf(m, v);
        }
        m = fmaxf(m, __shfl_xor(m, 1));
        m = fmaxf(m, __shfl_xor(m, 2));
        m = fmaxf(m, __shfl_xor(m, 4));
        m = fmaxf(m, __shfl_xor(m, 8));
        mx[i] = m;
      }
      #pragma unroll
      for (int i = 0; i < 4; ++i) {
        float s = 0.f;
        #pragma unroll
        for (int c = 0; c < 8; ++c) {
          float e = __expf(sT[i*8+c] - mx[i]);
          sT[i*8+c] = e; s += e;
        }
        s += __shfl_xor(s, 1);
        s += __shfl_xor(s, 2);
        s += __shfl_xor(s, 4);
        s += __shfl_xor(s, 8);
        float inv = 1.f / s;
        #pragma unroll
        for (int c = 0; c < 8; ++c) sT[i*8+c] *= inv;
      }
    }
    __syncthreads();                                   // scores reads done
    tstage(SB4, r0, ct, sT);                           // attn -> SB (over q)
    tstage(SA4, r0, ct, magT);                         // mag -> SA (over k)
    __syncthreads();
    float vT[32];
    wgemm<false>(SA4, r0, cb, Wvm_l, bvm + l * 128, vT);
    __syncthreads();                                   // SA mag reads done
    tstage(SA4, r0, ct, vT);                           // vm -> SA
    __syncthreads();
    float nT[32];
    avgemm(SB4, SA4, r0, ct, nT);                      // attn @ vm
    {                                                  // residual + LayerNorm
      float rs[4], rq[4];
      #pragma unroll
      for (int i = 0; i < 4; ++i) {
        float s = 0.f, q2 = 0.f;
        #pragma unroll
        for (int c = 0; c < 8; ++c) {
          float v = nT[i*8+c] + magT[i*8+c];
          nT[i*8+c] = v; s += v; q2 += v * v;
        }
        s  += __shfl_xor(s, 1);  s  += __shfl_xor(s, 2);
        s  += __shfl_xor(s, 4);  s  += __shfl_xor(s, 8);
        q2 += __shfl_xor(q2, 1); q2 += __shfl_xor(q2, 2);
        q2 += __shfl_xor(q2, 4); q2 += __shfl_xor(q2, 8);
        rs[i] = s; rq[i] = q2;
      }
      float4 g0 = *(const float4*)(ln_g + l * 128 + cb);
      float4 g1 = *(const float4*)(ln_g + l * 128 + cb + 4);
      float4 lb0 = *(const float4*)(ln_b + l * 128 + cb);
      float4 lb1 = *(const float4*)(ln_b + l * 128 + cb + 4);
      float gg[8] = {g0.x,g0.y,g0.z,g0.w,g1.x,g1.y,g1.z,g1.w};
      float bb[8] = {lb0.x,lb0.y,lb0.z,lb0.w,lb1.x,lb1.y,lb1.z,lb1.w};
      #pragma unroll
      for (int i = 0; i < 4; ++i) {
        float mu = rs[i] * (1.f / 128.f);
        float var = rq[i] * (1.f / 128.f) - mu * mu;
        float inv = 1.f / sqrtf(var + 1e-5f);
        #pragma unroll
        for (int c = 0; c < 8; ++c)
          magT[i*8+c] = gg[c] * ((nT[i*8+c] - mu) * inv) + bb[c];
      }
    }
    __syncthreads();                                   // SA vm reads done
    tstage(SA4, r0, ct, phT);                          // ph -> SA
    __syncthreads();
    wgemm<false>(SA4, r0, cb, Wvp_l, bvp + l * 128, vT);
    __syncthreads();                                   // SA ph reads done
    tstage(SA4, r0, ct, vT);                           // vp -> SA
    __syncthreads();
    avgemm(SB4, SA4, r0, ct, nT);                      // attn @ vp
    #pragma unroll
    for (int i = 0; i < 32; ++i) phT[i] += nT[i];
  } // layers

  // ---------------- real/imag -> RealProjection ----------------
  float reT[32], imT[32];
  #pragma unroll
  for (int i = 0; i < 32; ++i) {
    float s_, c_;
    __sincosf(phT[i], &s_, &c_);
    reT[i] = magT[i] * c_;
    imT[i] = magT[i] * s_;
  }
  __syncthreads();                                     // last layer readers done
  tstage(SA4, r0, ct, reT);
  tstage(SB4, r0, ct, imT);
  __syncthreads();
  float aT[32];
  wgemm<false>(SA4, r0, cb, rp_W, rp_b, aT);
  wgemm<true>(SB4, r0, cb, rp_W + (size_t)128 * 128, nullptr, aT);
  __syncthreads();                                     // rp reads done
  tstage(SA4, r0, ct, aT);                             // atom_repr -> SA
  __syncthreads();

  // ---------------- pooling + head ----------------
  float* SBf = (float*)SB4;
  {
    int c = t & 127, g = t >> 7;
    const float* SAf = (const float*)SA4;
    float ps = 0.f;
    #pragma unroll 8
    for (int i = 0; i < 32; ++i) {
      int row = g * 32 + i;
      ps += SAf[aidx(row, c >> 2) * 4 + (c & 3)];
    }
    SBf[g * 128 + c] = ps;
  }
  __syncthreads();
  if (t < 128) {
    float cs = SBf[t] + SBf[128 + t] + SBf[256 + t] + SBf[384 + t];
    SBf[t] = cs;                                       // column sum (sum-pool)
  }
  __syncthreads();
  if (t < 128) {
    float acc = h1_b[t];
    for (int i = 0; i < 128; ++i) {
      float cs = SBf[i];
      acc += cs * (h1_W[(size_t)i * 128 + t] * (1.f / 128.f) +
                   h1_W[(size_t)(128 + i) * 128 + t]);
    }
    float hv = acc / (1.f + __expf(-acc));             // SiLU
    SBf[128 + t] = hv * h2_W[t];
  }
  __syncthreads();
  if (t < 64) {
    float s2 = SBf[128 + t] + SBf[192 + t];
    #pragma unroll
    for (int off = 32; off >= 1; off >>= 1) s2 += __shfl_xor(s2, off);
    if (t == 0) out[b] = s2 + h2_b[0];
  }
}

extern "C" void kernel_launch(void* const* d_in, const int* in_sizes, int n_in,
                              void* d_out, int out_size, void* d_ws, size_t ws_size,
                              hipStream_t stream) {
  const float* atom_types = (const float*)d_in[0];
  const float* coords     = (const float*)d_in[1];
  const int*   edge_index = (const int*)  d_in[2];
  const float* edge_attr  = (const float*)d_in[3];
  const float* emb_Wm = (const float*)d_in[4];
  const float* emb_bm = (const float*)d_in[5];
  const float* emb_Wp = (const float*)d_in[6];
  const float* emb_bp = (const float*)d_in[7];
  const float* Wq  = (const float*)d_in[8];
  const float* bq  = (const float*)d_in[9];
  const float* Wk  = (const float*)d_in[10];
  const float* bk  = (const float*)d_in[11];
  const float* Wvm = (const float*)d_in[12];
  const float* bvm = (const float*)d_in[13];
  const float* Wvp = (const float*)d_in[14];
  const float* bvp = (const float*)d_in[15];
  const float* We  = (const float*)d_in[16];
  const float* be  = (const float*)d_in[17];
  const float* dist_scale = (const float*)d_in[18];
  const float* ln_g = (const float*)d_in[19];
  const float* ln_b = (const float*)d_in[20];
  const float* rp_W = (const float*)d_in[21];
  const float* rp_b = (const float*)d_in[22];
  const float* h1_W = (const float*)d_in[23];
  const float* h1_b = (const float*)d_in[24];
  const float* h2_W = (const float*)d_in[25];
  const float* h2_b = (const float*)d_in[26];
  float* out = (float*)d_out;

  hipLaunchKernelGGL(cpt_kernel, dim3(1024), dim3(512), 0, stream,
                     atom_types, coords, edge_index, edge_attr,
                     emb_Wm, emb_bm, emb_Wp, emb_bp,
                     Wq, bq, Wk, bk, Wvm, bvm, Wvp, bvp,
                     We, be, dist_scale, ln_g, ln_b,
                     rp_W, rp_b, h1_W, h1_b, h2_W, h2_b,
                     out);
}

// Round 3
// 2044.664 us; speedup vs baseline: 9.0986x; 1.0135x over previous
//
#include <hip/hip_runtime.h>
#include <math.h>

// ComplexPolarTransformerBeta — round 3.
// Round-2 structure (4x8 register tiling, two padded/swizzled LDS buffers) plus:
//  * __launch_bounds__(512,1): LDS already caps us at 1 block/CU (8 waves), so
//    allow up to 256 VGPRs -> no scratch spills (R2 had 81 MB scratch writes at
//    VGPR=128 because (512,2) was interpreted as 2 blocks/CU -> 128-reg cap).
//  * Edge bias cached in registers across layers: edge_index/edge_attr are
//    layer-invariant; precompute per-edge LDS slot + 4 per-layer bias values.

#define RS 33  // row stride in float4 units (128 floats data + 4 pad)

__device__ __forceinline__ int aidx(int row, int cf) {
  int slot = ((cf >> 1) | ((cf & 1) << 4));
  return row * RS + ((slot + (row >> 3)) & 31);
}

__device__ __forceinline__ void tstage(float4* S4, int r0, int ct, const float v[32]) {
  #pragma unroll
  for (int i = 0; i < 4; ++i) {
    S4[aidx(r0 + i, 2 * ct)]     = make_float4(v[i*8+0], v[i*8+1], v[i*8+2], v[i*8+3]);
    S4[aidx(r0 + i, 2 * ct + 1)] = make_float4(v[i*8+4], v[i*8+5], v[i*8+6], v[i*8+7]);
  }
}

__device__ __forceinline__ void tread(const float4* S4, int r0, int ct, float v[32]) {
  #pragma unroll
  for (int i = 0; i < 4; ++i) {
    float4 a = S4[aidx(r0 + i, 2 * ct)];
    float4 c = S4[aidx(r0 + i, 2 * ct + 1)];
    v[i*8+0] = a.x; v[i*8+1] = a.y; v[i*8+2] = a.z; v[i*8+3] = a.w;
    v[i*8+4] = c.x; v[i*8+5] = c.y; v[i*8+6] = c.z; v[i*8+7] = c.w;
  }
}

// out(4x8) = A(LDS rows r0..r0+3) @ W[128x128] (+ bias)
template<bool ACCUM>
__device__ __forceinline__ void wgemm(const float4* __restrict__ A4, int r0, int cb,
                                      const float* __restrict__ W,
                                      const float* __restrict__ bias, float out[32]) {
  if (!ACCUM) {
    float4 b0 = *(const float4*)(bias + cb);
    float4 b1 = *(const float4*)(bias + cb + 4);
    #pragma unroll
    for (int i = 0; i < 4; ++i) {
      out[i*8+0] = b0.x; out[i*8+1] = b0.y; out[i*8+2] = b0.z; out[i*8+3] = b0.w;
      out[i*8+4] = b1.x; out[i*8+5] = b1.y; out[i*8+6] = b1.z; out[i*8+7] = b1.w;
    }
  }
  #pragma unroll 2
  for (int k4 = 0; k4 < 32; ++k4) {
    float4 a0 = A4[aidx(r0 + 0, k4)];
    float4 a1 = A4[aidx(r0 + 1, k4)];
    float4 a2 = A4[aidx(r0 + 2, k4)];
    float4 a3 = A4[aidx(r0 + 3, k4)];
    #pragma unroll
    for (int kk = 0; kk < 4; ++kk) {
      const float* wr = W + (size_t)(k4 * 4 + kk) * 128 + cb;
      float4 w0 = *(const float4*)wr;
      float4 w1 = *(const float4*)(wr + 4);
      float av0 = kk==0?a0.x:kk==1?a0.y:kk==2?a0.z:a0.w;
      float av1 = kk==0?a1.x:kk==1?a1.y:kk==2?a1.z:a1.w;
      float av2 = kk==0?a2.x:kk==1?a2.y:kk==2?a2.z:a2.w;
      float av3 = kk==0?a3.x:kk==1?a3.y:kk==2?a3.z:a3.w;
      out[0]  += av0*w0.x; out[1]  += av0*w0.y; out[2]  += av0*w0.z; out[3]  += av0*w0.w;
      out[4]  += av0*w1.x; out[5]  += av0*w1.y; out[6]  += av0*w1.z; out[7]  += av0*w1.w;
      out[8]  += av1*w0.x; out[9]  += av1*w0.y; out[10] += av1*w0.z; out[11] += av1*w0.w;
      out[12] += av1*w1.x; out[13] += av1*w1.y; out[14] += av1*w1.z; out[15] += av1*w1.w;
      out[16] += av2*w0.x; out[17] += av2*w0.y; out[18] += av2*w0.z; out[19] += av2*w0.w;
      out[20] += av2*w1.x; out[21] += av2*w1.y; out[22] += av2*w1.z; out[23] += av2*w1.w;
      out[24] += av3*w0.x; out[25] += av3*w0.y; out[26] += av3*w0.z; out[27] += av3*w0.w;
      out[28] += av3*w1.x; out[29] += av3*w1.y; out[30] += av3*w1.z; out[31] += av3*w1.w;
    }
  }
}

// s(4x8) = Q(rows r0..+3) @ K(rows j0..+7)^T
__device__ __forceinline__ void scoresf(const float4* __restrict__ Q4,
                                        const float4* __restrict__ K4,
                                        int r0, int j0, float s[32]) {
  #pragma unroll
  for (int i = 0; i < 32; ++i) s[i] = 0.f;
  #pragma unroll 1
  for (int k4 = 0; k4 < 32; ++k4) {
    float4 q0 = Q4[aidx(r0 + 0, k4)];
    float4 q1 = Q4[aidx(r0 + 1, k4)];
    float4 q2 = Q4[aidx(r0 + 2, k4)];
    float4 q3 = Q4[aidx(r0 + 3, k4)];
    #pragma unroll
    for (int j = 0; j < 8; ++j) {
      float4 kv = K4[aidx(j0 + j, k4)];
      s[0*8+j] += q0.x*kv.x + q0.y*kv.y + q0.z*kv.z + q0.w*kv.w;
      s[1*8+j] += q1.x*kv.x + q1.y*kv.y + q1.z*kv.z + q1.w*kv.w;
      s[2*8+j] += q2.x*kv.x + q2.y*kv.y + q2.z*kv.z + q2.w*kv.w;
      s[3*8+j] += q3.x*kv.x + q3.y*kv.y + q3.z*kv.z + q3.w*kv.w;
    }
  }
}

// o(4x8) = P(rows r0..+3) @ V
__device__ __forceinline__ void avgemm(const float4* __restrict__ P4,
                                       const float4* __restrict__ V4,
                                       int r0, int ct, float o[32]) {
  #pragma unroll
  for (int i = 0; i < 32; ++i) o[i] = 0.f;
  #pragma unroll 1
  for (int j4 = 0; j4 < 32; ++j4) {
    float4 p0 = P4[aidx(r0 + 0, j4)];
    float4 p1 = P4[aidx(r0 + 1, j4)];
    float4 p2 = P4[aidx(r0 + 2, j4)];
    float4 p3 = P4[aidx(r0 + 3, j4)];
    #pragma unroll
    for (int jj = 0; jj < 4; ++jj) {
      int j = j4 * 4 + jj;
      float4 v0 = V4[aidx(j, 2 * ct)];
      float4 v1 = V4[aidx(j, 2 * ct + 1)];
      float pa = jj==0?p0.x:jj==1?p0.y:jj==2?p0.z:p0.w;
      float pb = jj==0?p1.x:jj==1?p1.y:jj==2?p1.z:p1.w;
      float pc = jj==0?p2.x:jj==1?p2.y:jj==2?p2.z:p2.w;
      float pd = jj==0?p3.x:jj==1?p3.y:jj==2?p3.z:p3.w;
      o[0]  += pa*v0.x; o[1]  += pa*v0.y; o[2]  += pa*v0.z; o[3]  += pa*v0.w;
      o[4]  += pa*v1.x; o[5]  += pa*v1.y; o[6]  += pa*v1.z; o[7]  += pa*v1.w;
      o[8]  += pb*v0.x; o[9]  += pb*v0.y; o[10] += pb*v0.z; o[11] += pb*v0.w;
      o[12] += pb*v1.x; o[13] += pb*v1.y; o[14] += pb*v1.z; o[15] += pb*v1.w;
      o[16] += pc*v0.x; o[17] += pc*v0.y; o[18] += pc*v0.z; o[19] += pc*v0.w;
      o[20] += pc*v1.x; o[21] += pc*v1.y; o[22] += pc*v1.z; o[23] += pc*v1.w;
      o[24] += pd*v0.x; o[25] += pd*v0.y; o[26] += pd*v0.z; o[27] += pd*v0.w;
      o[28] += pd*v1.x; o[29] += pd*v1.y; o[30] += pd*v1.z; o[31] += pd*v1.w;
    }
  }
}

__global__ __launch_bounds__(512, 1)
void cpt_kernel(const float* __restrict__ atom_types,
                const float* __restrict__ coords,
                const int*   __restrict__ edge_index,
                const float* __restrict__ edge_attr,
                const float* __restrict__ emb_Wm, const float* __restrict__ emb_bm,
                const float* __restrict__ emb_Wp, const float* __restrict__ emb_bp,
                const float* __restrict__ Wq,  const float* __restrict__ bq,
                const float* __restrict__ Wk,  const float* __restrict__ bk,
                const float* __restrict__ Wvm, const float* __restrict__ bvm,
                const float* __restrict__ Wvp, const float* __restrict__ bvp,
                const float* __restrict__ We,  const float* __restrict__ be,
                const float* __restrict__ dist_scale,
                const float* __restrict__ ln_g, const float* __restrict__ ln_b,
                const float* __restrict__ rp_W, const float* __restrict__ rp_b,
                const float* __restrict__ h1_W, const float* __restrict__ h1_b,
                const float* __restrict__ h2_W, const float* __restrict__ h2_b,
                float* __restrict__ out)
{
  __shared__ float4 SA4[128 * RS];
  __shared__ float4 SB4[128 * RS];

  const int t = threadIdx.x;
  const int b = blockIdx.x;
  const int rt = t >> 4, ct = t & 15;
  const int r0 = rt * 4, cb = ct * 8;

  float magT[32], phT[32];

  // ---------------- edge gather (once; layer-invariant indices) ----------------
  int   efi[2];
  float ebv[2][4];
  {
    #pragma unroll
    for (int eo = 0; eo < 2; ++eo) {
      int e = t + eo * 512;
      int ei0 = edge_index[(size_t)b * 2048 + e];
      int ei1 = edge_index[(size_t)b * 2048 + 1024 + e];
      float4 ea = *(const float4*)(edge_attr + ((size_t)b * 1024 + e) * 4);
      efi[eo] = aidx(ei0, ei1 >> 2) * 4 + (ei1 & 3);
      #pragma unroll
      for (int l = 0; l < 4; ++l) {
        ebv[eo][l] = ea.x * We[l*4+0] + ea.y * We[l*4+1] +
                     ea.z * We[l*4+2] + ea.w * We[l*4+3] +
                     be[l] + dist_scale[l] * ea.x;
      }
    }
  }

  // ---------------- embedding (tile layout) ----------------
  {
    float4 bm0 = *(const float4*)(emb_bm + cb);
    float4 bm1 = *(const float4*)(emb_bm + cb + 4);
    float4 bp0 = *(const float4*)(emb_bp + cb);
    float4 bp1 = *(const float4*)(emb_bp + cb + 4);
    #pragma unroll 1
    for (int i = 0; i < 4; ++i) {
      int row = r0 + i;
      float x[19];
      const float* at = atom_types + ((size_t)b * 128 + row) * 16;
      #pragma unroll
      for (int q = 0; q < 4; ++q) {
        float4 v = *(const float4*)(at + 4 * q);
        x[4*q+0] = v.x; x[4*q+1] = v.y; x[4*q+2] = v.z; x[4*q+3] = v.w;
      }
      const float* cs = coords + ((size_t)b * 128 + row) * 3;
      x[16] = cs[0]; x[17] = cs[1]; x[18] = cs[2];
      float m[8] = {bm0.x,bm0.y,bm0.z,bm0.w,bm1.x,bm1.y,bm1.z,bm1.w};
      float p[8] = {bp0.x,bp0.y,bp0.z,bp0.w,bp1.x,bp1.y,bp1.z,bp1.w};
      #pragma unroll 1
      for (int d = 0; d < 19; ++d) {
        float xv = x[d];
        const float* wm = emb_Wm + d * 128 + cb;
        const float* wp = emb_Wp + d * 128 + cb;
        float4 a0 = *(const float4*)wm, a1 = *(const float4*)(wm + 4);
        float4 c0 = *(const float4*)wp, c1 = *(const float4*)(wp + 4);
        m[0]+=xv*a0.x; m[1]+=xv*a0.y; m[2]+=xv*a0.z; m[3]+=xv*a0.w;
        m[4]+=xv*a1.x; m[5]+=xv*a1.y; m[6]+=xv*a1.z; m[7]+=xv*a1.w;
        p[0]+=xv*c0.x; p[1]+=xv*c0.y; p[2]+=xv*c0.z; p[3]+=xv*c0.w;
        p[4]+=xv*c1.x; p[5]+=xv*c1.y; p[6]+=xv*c1.z; p[7]+=xv*c1.w;
      }
      #pragma unroll
      for (int c = 0; c < 8; ++c) { magT[i*8+c] = m[c]; phT[i*8+c] = p[c]; }
    }
  }

  const float scale = 0.08838834764831845f;  // 1/sqrt(128)

  for (int l = 0; l < 4; ++l) {
    const float* Wq_l  = Wq  + (size_t)l * 16384;
    const float* Wk_l  = Wk  + (size_t)l * 16384;
    const float* Wvm_l = Wvm + (size_t)l * 16384;
    const float* Wvp_l = Wvp + (size_t)l * 16384;

    __syncthreads();                                   // prev layer's readers done
    {                                                  // zero SB (bias buffer)
      float4 z = make_float4(0.f, 0.f, 0.f, 0.f);
      #pragma unroll
      for (int k = 0; k < 9; ++k) {
        int idx = t + k * 512;
        if (idx < 128 * RS) SB4[idx] = z;
      }
    }
    tstage(SA4, r0, ct, magT);                         // mag -> SA
    __syncthreads();
    atomicAdd((float*)SB4 + efi[0], ebv[0][l]);        // edge-bias scatter -> SB
    atomicAdd((float*)SB4 + efi[1], ebv[1][l]);
    __syncthreads();
    float bT[32];
    tread(SB4, r0, ct, bT);                            // bias tile -> regs
    float qT[32];
    wgemm<false>(SA4, r0, cb, Wq_l, bq + l * 128, qT); // q = mag@Wq
    __syncthreads();                                   // bias reads done
    tstage(SB4, r0, ct, qT);                           // q -> SB
    {
      float kT[32];
      wgemm<false>(SA4, r0, cb, Wk_l, bk + l * 128, kT);
      __syncthreads();                                 // SA reads + SB q-writes done
      tstage(SA4, r0, ct, kT);                         // k -> SA (over mag)
    }
    __syncthreads();
    float sT[32];
    scoresf(SB4, SA4, r0, cb, sT);                     // q @ k^T
    {                                                  // + bias, softmax per row
      float mx[4];
      #pragma unroll
      for (int i = 0; i < 4; ++i) {
        float m = -1e30f;
        #pragma unroll
        for (int c = 0; c < 8; ++c) {
          float v = bT[i*8+c] + scale * sT[i*8+c];
          sT[i*8+c] = v;
          m = fmaxf(m, v);
        }
        m = fmaxf(m, __shfl_xor(m, 1));
        m = fmaxf(m, __shfl_xor(m, 2));
        m = fmaxf(m, __shfl_xor(m, 4));
        m = fmaxf(m, __shfl_xor(m, 8));
        mx[i] = m;
      }
      #pragma unroll
      for (int i = 0; i < 4; ++i) {
        float s = 0.f;
        #pragma unroll
        for (int c = 0; c < 8; ++c) {
          float e = __expf(sT[i*8+c] - mx[i]);
          sT[i*8+c] = e; s += e;
        }
        s += __shfl_xor(s, 1);
        s += __shfl_xor(s, 2);
        s += __shfl_xor(s, 4);
        s += __shfl_xor(s, 8);
        float inv = 1.f / s;
        #pragma unroll
        for (int c = 0; c < 8; ++c) sT[i*8+c] *= inv;
      }
    }
    __syncthreads();                                   // scores reads done
    tstage(SB4, r0, ct, sT);                           // attn -> SB (over q)
    tstage(SA4, r0, ct, magT);                         // mag -> SA (over k)
    __syncthreads();
    float vT[32];
    wgemm<false>(SA4, r0, cb, Wvm_l, bvm + l * 128, vT);
    __syncthreads();                                   // SA mag reads done
    tstage(SA4, r0, ct, vT);                           // vm -> SA
    __syncthreads();
    float nT[32];
    avgemm(SB4, SA4, r0, ct, nT);                      // attn @ vm
    {                                                  // residual + LayerNorm
      float rs[4], rq[4];
      #pragma unroll
      for (int i = 0; i < 4; ++i) {
        float s = 0.f, q2 = 0.f;
        #pragma unroll
        for (int c = 0; c < 8; ++c) {
          float v = nT[i*8+c] + magT[i*8+c];
          nT[i*8+c] = v; s += v; q2 += v * v;
        }
        s  += __shfl_xor(s, 1);  s  += __shfl_xor(s, 2);
        s  += __shfl_xor(s, 4);  s  += __shfl_xor(s, 8);
        q2 += __shfl_xor(q2, 1); q2 += __shfl_xor(q2, 2);
        q2 += __shfl_xor(q2, 4); q2 += __shfl_xor(q2, 8);
        rs[i] = s; rq[i] = q2;
      }
      float4 g0 = *(const float4*)(ln_g + l * 128 + cb);
      float4 g1 = *(const float4*)(ln_g + l * 128 + cb + 4);
      float4 lb0 = *(const float4*)(ln_b + l * 128 + cb);
      float4 lb1 = *(const float4*)(ln_b + l * 128 + cb + 4);
      float gg[8] = {g0.x,g0.y,g0.z,g0.w,g1.x,g1.y,g1.z,g1.w};
      float bb[8] = {lb0.x,lb0.y,lb0.z,lb0.w,lb1.x,lb1.y,lb1.z,lb1.w};
      #pragma unroll
      for (int i = 0; i < 4; ++i) {
        float mu = rs[i] * (1.f / 128.f);
        float var = rq[i] * (1.f / 128.f) - mu * mu;
        float inv = 1.f / sqrtf(var + 1e-5f);
        #pragma unroll
        for (int c = 0; c < 8; ++c)
          magT[i*8+c] = gg[c] * ((nT[i*8+c] - mu) * inv) + bb[c];
      }
    }
    __syncthreads();                                   // SA vm reads done
    tstage(SA4, r0, ct, phT);                          // ph -> SA
    __syncthreads();
    wgemm<false>(SA4, r0, cb, Wvp_l, bvp + l * 128, vT);
    __syncthreads();                                   // SA ph reads done
    tstage(SA4, r0, ct, vT);                           // vp -> SA
    __syncthreads();
    avgemm(SB4, SA4, r0, ct, nT);                      // attn @ vp
    #pragma unroll
    for (int i = 0; i < 32; ++i) phT[i] += nT[i];
  } // layers

  // ---------------- real/imag -> RealProjection ----------------
  float reT[32], imT[32];
  #pragma unroll
  for (int i = 0; i < 32; ++i) {
    float s_, c_;
    __sincosf(phT[i], &s_, &c_);
    reT[i] = magT[i] * c_;
    imT[i] = magT[i] * s_;
  }
  __syncthreads();                                     // last layer readers done
  tstage(SA4, r0, ct, reT);
  tstage(SB4, r0, ct, imT);
  __syncthreads();
  float aT[32];
  wgemm<false>(SA4, r0, cb, rp_W, rp_b, aT);
  wgemm<true>(SB4, r0, cb, rp_W + (size_t)128 * 128, nullptr, aT);
  __syncthreads();                                     // rp reads done
  tstage(SA4, r0, ct, aT);                             // atom_repr -> SA
  __syncthreads();

  // ---------------- pooling + head ----------------
  float* SBf = (float*)SB4;
  {
    int c = t & 127, g = t >> 7;
    const float* SAf = (const float*)SA4;
    float ps = 0.f;
    #pragma unroll 8
    for (int i = 0; i < 32; ++i) {
      int row = g * 32 + i;
      ps += SAf[aidx(row, c >> 2) * 4 + (c & 3)];
    }
    SBf[g * 128 + c] = ps;
  }
  __syncthreads();
  if (t < 128) {
    float cs = SBf[t] + SBf[128 + t] + SBf[256 + t] + SBf[384 + t];
    SBf[t] = cs;                                       // column sum (sum-pool)
  }
  __syncthreads();
  if (t < 128) {
    float acc = h1_b[t];
    for (int i = 0; i < 128; ++i) {
      float cs = SBf[i];
      acc += cs * (h1_W[(size_t)i * 128 + t] * (1.f / 128.f) +
                   h1_W[(size_t)(128 + i) * 128 + t]);
    }
    float hv = acc / (1.f + __expf(-acc));             // SiLU
    SBf[128 + t] = hv * h2_W[t];
  }
  __syncthreads();
  if (t < 64) {
    float s2 = SBf[128 + t] + SBf[192 + t];
    #pragma unroll
    for (int off = 32; off >= 1; off >>= 1) s2 += __shfl_xor(s2, off);
    if (t == 0) out[b] = s2 + h2_b[0];
  }
}

extern "C" void kernel_launch(void* const* d_in, const int* in_sizes, int n_in,
                              void* d_out, int out_size, void* d_ws, size_t ws_size,
                              hipStream_t stream) {
  const float* atom_types = (const float*)d_in[0];
  const float* coords     = (const float*)d_in[1];
  const int*   edge_index = (const int*)  d_in[2];
  const float* edge_attr  = (const float*)d_in[3];
  const float* emb_Wm = (const float*)d_in[4];
  const float* emb_bm = (const float*)d_in[5];
  const float* emb_Wp = (const float*)d_in[6];
  const float* emb_bp = (const float*)d_in[7];
  const float* Wq  = (const float*)d_in[8];
  const float* bq  = (const float*)d_in[9];
  const float* Wk  = (const float*)d_in[10];
  const float* bk  = (const float*)d_in[11];
  const float* Wvm = (const float*)d_in[12];
  const float* bvm = (const float*)d_in[13];
  const float* Wvp = (const float*)d_in[14];
  const float* bvp = (const float*)d_in[15];
  const float* We  = (const float*)d_in[16];
  const float* be  = (const float*)d_in[17];
  const float* dist_scale = (const float*)d_in[18];
  const float* ln_g = (const float*)d_in[19];
  const float* ln_b = (const float*)d_in[20];
  const float* rp_W = (const float*)d_in[21];
  const float* rp_b = (const float*)d_in[22];
  const float* h1_W = (const float*)d_in[23];
  const float* h1_b = (const float*)d_in[24];
  const float* h2_W = (const float*)d_in[25];
  const float* h2_b = (const float*)d_in[26];
  float* out = (float*)d_out;

  hipLaunchKernelGGL(cpt_kernel, dim3(1024), dim3(512), 0, stream,
                     atom_types, coords, edge_index, edge_attr,
                     emb_Wm, emb_bm, emb_Wp, emb_bp,
                     Wq, bq, Wk, bk, Wvm, bvm, Wvp, bvp,
                     We, be, dist_scale, ln_g, ln_b,
                     rp_W, rp_b, h1_W, h1_b, h2_W, h2_b,
                     out);
}

// Round 4
// 1050.559 us; speedup vs baseline: 17.7083x; 1.9463x over previous
//
#include <hip/hip_runtime.h>
#include <math.h>

// ComplexPolarTransformerBeta — round 4: MFMA (bf16 hi/lo split-3 emulated fp32).
// One block per molecule, 512 threads = 8 waves. All 128x128x128 GEMMs use
// v_mfma_f32_32x32x16_bf16. Wave w: m-block = 32*(w>>1), n-half = 64*(w&1)
// (two 32-col tiles tl=0,1). C/D layout: col=lane&31, row=(reg&3)+8*(reg>>2)+4*(lane>>5).
// A-frag: m=lane&31, k=(lane>>5)*8+j (contig-k 16B). B-frag: n=lane&31, same k.
// Weights preprocessed per launch into fragment-ordered bf16 hi/lo in d_ws.

typedef __attribute__((ext_vector_type(8)))  short s16x8;
typedef __attribute__((ext_vector_type(16))) float f32x16;

#define STR  136      // LDS row stride (shorts / floats): 128 data + 8 pad, 16B-aligned rows
#define LOFS 17408    // offset of lo-array within a region (128*136 shorts)
#define MFMA(a, b, c) __builtin_amdgcn_mfma_f32_32x32x16_bf16(a, b, c, 0, 0, 0)
#define ROWP(reg) (((reg) & 3) + (((reg) >> 2) << 3) + (h5 << 2))

__device__ __forceinline__ unsigned short bfhi(float x) {
  unsigned u = __float_as_uint(x);
  return (unsigned short)((u + 0x7FFFu + ((u >> 16) & 1u)) >> 16);
}
__device__ __forceinline__ float bf2f(unsigned short h) {
  return __uint_as_float(((unsigned)h) << 16);
}

// Stage C-layout acc into S[row=n][col=m] bf16 hi/lo (packed b64 over reg-quads).
__device__ __forceinline__ void stageB64(short* SH, const f32x16 acc[2],
                                         int nb0, int l31, int h5, int mblk, float scl) {
  #pragma unroll
  for (int tl = 0; tl < 2; ++tl) {
    int row = nb0 + 32 * tl + l31;
    #pragma unroll
    for (int q = 0; q < 4; ++q) {
      int col = mblk + 8 * q + 4 * h5;
      float v0 = acc[tl][4*q+0] * scl, v1 = acc[tl][4*q+1] * scl;
      float v2 = acc[tl][4*q+2] * scl, v3 = acc[tl][4*q+3] * scl;
      unsigned short h0 = bfhi(v0), h1 = bfhi(v1), h2 = bfhi(v2), h3 = bfhi(v3);
      short4 hv = make_short4((short)h0, (short)h1, (short)h2, (short)h3);
      short4 lv = make_short4((short)bfhi(v0 - bf2f(h0)), (short)bfhi(v1 - bf2f(h1)),
                              (short)bfhi(v2 - bf2f(h2)), (short)bfhi(v3 - bf2f(h3)));
      *(short4*)(SH + row * STR + col) = hv;
      *(short4*)(SH + LOFS + row * STR + col) = lv;
    }
  }
}

// Stage per-thread state v[32] (C-layout: row a per reg, col h per tl/lane) into S[a][h].
__device__ __forceinline__ void stageScatter(short* SH, const float* v,
                                             int nb0, int l31, int h5, int mblk) {
  #pragma unroll
  for (int tl = 0; tl < 2; ++tl) {
    int col = nb0 + 32 * tl + l31;
    #pragma unroll
    for (int reg = 0; reg < 16; ++reg) {
      int row = mblk + ROWP(reg);
      float x = v[tl * 16 + reg];
      unsigned short h = bfhi(x);
      SH[row * STR + col] = (short)h;
      SH[LOFS + row * STR + col] = (short)bfhi(x - bf2f(h));
    }
  }
}

// D[m][n] += A(LDS)[m][k] * B(LDS)^T[k][n]  (both operands [row][k-contig] bf16 hi/lo)
__device__ __forceinline__ void gemmLL(f32x16 acc[2], const short* AH, const short* BH,
                                       int mblk, int nb0, int l31, int h5) {
  int arow = mblk + l31;
  #pragma unroll
  for (int kb = 0; kb < 8; ++kb) {
    int k0 = kb * 16 + 8 * h5;
    s16x8 ah = *(const s16x8*)(AH + arow * STR + k0);
    s16x8 al = *(const s16x8*)(AH + LOFS + arow * STR + k0);
    #pragma unroll
    for (int tl = 0; tl < 2; ++tl) {
      int brow = nb0 + 32 * tl + l31;
      s16x8 bh = *(const s16x8*)(BH + brow * STR + k0);
      s16x8 bl = *(const s16x8*)(BH + LOFS + brow * STR + k0);
      acc[tl] = MFMA(ah, bh, acc[tl]);
      acc[tl] = MFMA(ah, bl, acc[tl]);
      acc[tl] = MFMA(al, bh, acc[tl]);
    }
  }
}

// D[m=a][n=h]: A = LDS activation rows a, B = preprocessed weight (frag-ordered).
__device__ __forceinline__ void gemmNW(f32x16 acc[2], const short* AH, const short* W,
                                       int mblk, int w1, int l31, int h5, int lane) {
  int arow = mblk + l31;
  #pragma unroll
  for (int kb = 0; kb < 8; ++kb) {
    int k0 = kb * 16 + 8 * h5;
    s16x8 ah = *(const s16x8*)(AH + arow * STR + k0);
    s16x8 al = *(const s16x8*)(AH + LOFS + arow * STR + k0);
    #pragma unroll
    for (int tl = 0; tl < 2; ++tl) {
      int hblk = 2 * w1 + tl;
      const short* wp = W + (((hblk * 8 + kb) * 64 + lane) * 8);
      s16x8 bh = *(const s16x8*)wp;
      s16x8 bl = *(const s16x8*)(wp + 32768);
      acc[tl] = MFMA(ah, bh, acc[tl]);
      acc[tl] = MFMA(ah, bl, acc[tl]);
      acc[tl] = MFMA(al, bh, acc[tl]);
    }
  }
}

// D[m=h][n=i]: A = preprocessed weight (m-tile = w>>1), B = LDS activation rows i.
__device__ __forceinline__ void gemmTW(f32x16 acc[2], const short* W, const short* BH,
                                       int mt, int nb0, int l31, int h5, int lane) {
  #pragma unroll
  for (int kb = 0; kb < 8; ++kb) {
    int k0 = kb * 16 + 8 * h5;
    const short* wp = W + (((mt * 8 + kb) * 64 + lane) * 8);
    s16x8 ah = *(const s16x8*)wp;
    s16x8 al = *(const s16x8*)(wp + 32768);
    #pragma unroll
    for (int tl = 0; tl < 2; ++tl) {
      int brow = nb0 + 32 * tl + l31;
      s16x8 bh = *(const s16x8*)(BH + brow * STR + k0);
      s16x8 bl = *(const s16x8*)(BH + LOFS + brow * STR + k0);
      acc[tl] = MFMA(ah, bh, acc[tl]);
      acc[tl] = MFMA(ah, bl, acc[tl]);
      acc[tl] = MFMA(al, bh, acc[tl]);
    }
  }
}

// ---------------- weight preprocessing: fp32 [k][h] -> frag-ordered bf16 hi/lo ----------
__global__ __launch_bounds__(512)
void prep_kernel(const float* __restrict__ Wq, const float* __restrict__ Wk,
                 const float* __restrict__ Wvm, const float* __restrict__ Wvp,
                 const float* __restrict__ rp_W, short* __restrict__ ws) {
  int mid = blockIdx.x >> 2, hblk = blockIdx.x & 3;
  int kb = threadIdx.x >> 6, lane = threadIdx.x & 63;
  const float* src;
  if (mid < 4)       src = Wq  + mid * 16384;
  else if (mid < 8)  src = Wk  + (mid - 4) * 16384;
  else if (mid < 12) src = Wvm + (mid - 8) * 16384;
  else if (mid < 16) src = Wvp + (mid - 12) * 16384;
  else if (mid == 16) src = rp_W;
  else                src = rp_W + 16384;
  int h = hblk * 32 + (lane & 31);
  int kbase = kb * 16 + ((lane >> 5) << 3);
  s16x8 H, L;
  #pragma unroll
  for (int j = 0; j < 8; ++j) {
    float v = src[(size_t)(kbase + j) * 128 + h];
    unsigned short hi = bfhi(v);
    H[j] = (short)hi;
    L[j] = (short)bfhi(v - bf2f(hi));
  }
  short* dst = ws + (size_t)mid * 65536 + ((hblk * 8 + kb) * 64 + lane) * 8;
  *(s16x8*)dst = H;
  *(s16x8*)(dst + 32768) = L;
}

// ---------------- main kernel ----------------
__global__ __launch_bounds__(512, 2)
void cpt_kernel(const float* __restrict__ atom_types,
                const float* __restrict__ coords,
                const int*   __restrict__ edge_index,
                const float* __restrict__ edge_attr,
                const float* __restrict__ emb_Wm, const float* __restrict__ emb_bm,
                const float* __restrict__ emb_Wp, const float* __restrict__ emb_bp,
                const float* __restrict__ bq, const float* __restrict__ bk,
                const float* __restrict__ bvm, const float* __restrict__ bvp,
                const float* __restrict__ We,  const float* __restrict__ be,
                const float* __restrict__ dist_scale,
                const float* __restrict__ ln_g, const float* __restrict__ ln_b,
                const float* __restrict__ rp_b,
                const float* __restrict__ h1_W, const float* __restrict__ h1_b,
                const float* __restrict__ h2_W, const float* __restrict__ h2_b,
                const short* __restrict__ wpre,
                float* __restrict__ out)
{
  __shared__ __align__(16) short R1s[34816];   // 69,632 B region
  __shared__ __align__(16) short R2s[34816];   // 69,632 B region
  __shared__ float SCa[512];
  __shared__ float SCb[512];

  const int t = threadIdx.x, b = blockIdx.x;
  const int w = t >> 6, lane = t & 63, l31 = lane & 31, h5 = lane >> 5;
  const int mblk = (w >> 1) << 5;   // m-block base (rows of D)
  const int w1 = w & 1;
  const int nb0 = w1 << 6;          // n-half base (cols of D)
  const float scale = 0.08838834764831845f;  // 1/sqrt(128)

  // ---- edge gather (layer-invariant) ----
  int efA, efB; float4 eaA, eaB;
  {
    int e0 = t, e1 = t + 512;
    int i0 = edge_index[(size_t)b * 2048 + e0];
    int j0 = edge_index[(size_t)b * 2048 + 1024 + e0];
    int i1 = edge_index[(size_t)b * 2048 + e1];
    int j1 = edge_index[(size_t)b * 2048 + 1024 + e1];
    efA = i0 * STR + j0;  efB = i1 * STR + j1;
    eaA = *(const float4*)(edge_attr + ((size_t)b * 1024 + e0) * 4);
    eaB = *(const float4*)(edge_attr + ((size_t)b * 1024 + e1) * 4);
  }

  // ---- embedding -> magP/phP (C-layout: a = mblk+ROWP(reg), h = nb0+32*tl+l31) ----
  float magP[32], phP[32];
  {
    float wmv0[19], wpv0[19], wmv1[19], wpv1[19];
    int h0 = nb0 + l31, h1 = nb0 + 32 + l31;
    #pragma unroll
    for (int d = 0; d < 19; ++d) {
      wmv0[d] = emb_Wm[d * 128 + h0]; wpv0[d] = emb_Wp[d * 128 + h0];
      wmv1[d] = emb_Wm[d * 128 + h1]; wpv1[d] = emb_Wp[d * 128 + h1];
    }
    float bm0 = emb_bm[h0], bp0 = emb_bp[h0], bm1 = emb_bm[h1], bp1 = emb_bp[h1];
    #pragma unroll
    for (int reg = 0; reg < 16; ++reg) {
      int a = mblk + ROWP(reg);
      const float* xr = atom_types + ((size_t)b * 128 + a) * 16;
      float x[19];
      float4 v0 = *(const float4*)xr,      v1 = *(const float4*)(xr + 4);
      float4 v2 = *(const float4*)(xr + 8), v3 = *(const float4*)(xr + 12);
      x[0]=v0.x; x[1]=v0.y; x[2]=v0.z; x[3]=v0.w;
      x[4]=v1.x; x[5]=v1.y; x[6]=v1.z; x[7]=v1.w;
      x[8]=v2.x; x[9]=v2.y; x[10]=v2.z; x[11]=v2.w;
      x[12]=v3.x; x[13]=v3.y; x[14]=v3.z; x[15]=v3.w;
      const float* cr = coords + ((size_t)b * 128 + a) * 3;
      x[16]=cr[0]; x[17]=cr[1]; x[18]=cr[2];
      float m0 = bm0, p0 = bp0, m1 = bm1, p1 = bp1;
      #pragma unroll
      for (int d = 0; d < 19; ++d) {
        m0 += x[d] * wmv0[d]; p0 += x[d] * wpv0[d];
        m1 += x[d] * wmv1[d]; p1 += x[d] * wpv1[d];
      }
      magP[reg] = m0; phP[reg] = p0; magP[16 + reg] = m1; phP[16 + reg] = p1;
    }
  }

  // ---- layers ----
  for (int l = 0; l < 4; ++l) {
    const short* wqP  = wpre + (size_t)l * 65536;
    const short* wkP  = wpre + (size_t)(4 + l) * 65536;
    const short* wvmP = wpre + (size_t)(8 + l) * 65536;
    const short* wvpP = wpre + (size_t)(12 + l) * 65536;
    float we0 = We[l*4], we1 = We[l*4+1], we2 = We[l*4+2], we3 = We[l*4+3];
    float bel = be[l], dsl = dist_scale[l];

    __syncthreads();                       // prior readers of R1/R2 done
    float* biasF = (float*)R1s;            // fp32 [128][STR] bias matrix
    {
      float4* z4 = (float4*)R1s;
      #pragma unroll
      for (int k = 0; k < 9; ++k) { int idx = t + 512 * k; if (idx < 4352) z4[idx] = make_float4(0.f,0.f,0.f,0.f); }
    }
    __syncthreads();
    {
      float bvA = eaA.x*we0 + eaA.y*we1 + eaA.z*we2 + eaA.w*we3 + bel + dsl*eaA.x;
      float bvB = eaB.x*we0 + eaB.y*we1 + eaB.z*we2 + eaB.w*we3 + bel + dsl*eaB.x;
      atomicAdd(&biasF[efA], bvA);
      atomicAdd(&biasF[efB], bvB);
    }
    __syncthreads();
    // preload scores acc with bias (scoresT layout: m=j=mblk+ROWP, n=i=nb0+32tl+l31)
    f32x16 accS[2];
    #pragma unroll
    for (int tl = 0; tl < 2; ++tl) {
      int i = nb0 + 32 * tl + l31;
      #pragma unroll
      for (int reg = 0; reg < 16; ++reg)
        accS[tl][reg] = biasF[i * STR + (mblk + ROWP(reg))];
    }
    __syncthreads();                       // bias reads done before mag overwrites R1
    stageScatter(R1s, magP, nb0, l31, h5, mblk);   // mag -> R1 [a][h]
    __syncthreads();

    // Q^T = Wq^T x mag^T  (D[h][i]);  init bq[h=mblk+ROWP]
    {
      f32x16 accQ[2];
      #pragma unroll
      for (int reg = 0; reg < 16; ++reg) {
        float bv = bq[l * 128 + mblk + ROWP(reg)];
        accQ[0][reg] = bv; accQ[1][reg] = bv;
      }
      gemmTW(accQ, wqP, R1s, w >> 1, nb0, l31, h5, lane);
      stageB64(R2s, accQ, nb0, l31, h5, mblk, scale);  // (scale*Q)[i][h] -> R2
    }
    // vm = mag @ Wvm (D[a][h]); init bvm[h]
    f32x16 accVM[2];
    {
      #pragma unroll
      for (int tl = 0; tl < 2; ++tl) {
        float bv = bvm[l * 128 + nb0 + 32 * tl + l31];
        #pragma unroll
        for (int reg = 0; reg < 16; ++reg) accVM[tl][reg] = bv;
      }
      gemmNW(accVM, R1s, wvmP, mblk, w1, l31, h5, lane);
    }
    // K^T (D[h][j]); init bk
    f32x16 accK[2];
    {
      #pragma unroll
      for (int reg = 0; reg < 16; ++reg) {
        float bv = bk[l * 128 + mblk + ROWP(reg)];
        accK[0][reg] = bv; accK[1][reg] = bv;
      }
      gemmTW(accK, wkP, R1s, w >> 1, nb0, l31, h5, lane);
    }
    __syncthreads();                       // mag reads + Q writes done
    stageB64(R1s, accK, nb0, l31, h5, mblk, 1.0f);   // K[j][h] -> R1 (over mag)
    __syncthreads();

    // scoresT[j][i] = K @ (scale*Q)^T + bias(preloaded)
    gemmLL(accS, R1s, R2s, mblk, nb0, l31, h5);

    // softmax over j (regs + h5-partner + 4 m-block waves)
    #pragma unroll
    for (int tl = 0; tl < 2; ++tl) {
      float m = accS[tl][0];
      #pragma unroll
      for (int reg = 1; reg < 16; ++reg) m = fmaxf(m, accS[tl][reg]);
      m = fmaxf(m, __shfl_xor(m, 32));
      if (h5 == 0) SCa[(w >> 1) * 128 + nb0 + 32 * tl + l31] = m;
    }
    __syncthreads();
    float inv_s[2];
    #pragma unroll
    for (int tl = 0; tl < 2; ++tl) {
      int i = nb0 + 32 * tl + l31;
      float mg = fmaxf(fmaxf(SCa[i], SCa[128 + i]), fmaxf(SCa[256 + i], SCa[384 + i]));
      float s = 0.f;
      #pragma unroll
      for (int reg = 0; reg < 16; ++reg) {
        float e = __expf(accS[tl][reg] - mg);
        accS[tl][reg] = e; s += e;
      }
      s += __shfl_xor(s, 32);
      if (h5 == 0) SCb[(w >> 1) * 128 + i] = s;
    }
    __syncthreads();
    #pragma unroll
    for (int tl = 0; tl < 2; ++tl) {
      int i = nb0 + 32 * tl + l31;
      float sg = SCb[i] + SCb[128 + i] + SCb[256 + i] + SCb[384 + i];
      inv_s[tl] = 1.f / sg;
      #pragma unroll
      for (int reg = 0; reg < 16; ++reg) accS[tl][reg] *= inv_s[tl];
    }
    __syncthreads();                       // all scores reads of R1/R2 done
    stageB64(R2s, accS, nb0, l31, h5, mblk, 1.0f);   // attn[i][j] -> R2 (over Q)
    stageB64(R1s, accVM, nb0, l31, h5, mblk, 1.0f);  // vm[h][a]  -> R1 (over K)
    __syncthreads();

    // new_mag = attn @ vm + mag (init acc = magP)
    f32x16 accM[2];
    #pragma unroll
    for (int tl = 0; tl < 2; ++tl)
      #pragma unroll
      for (int reg = 0; reg < 16; ++reg) accM[tl][reg] = magP[tl * 16 + reg];
    gemmLL(accM, R2s, R1s, mblk, nb0, l31, h5);

    // LayerNorm over h
    {
      float sv[16], qv[16];
      #pragma unroll
      for (int reg = 0; reg < 16; ++reg) {
        float a0 = accM[0][reg], a1 = accM[1][reg];
        float s = a0 + a1, q = a0 * a0 + a1 * a1;
        #pragma unroll
        for (int off = 1; off < 32; off <<= 1) { s += __shfl_xor(s, off); q += __shfl_xor(q, off); }
        sv[reg] = s; qv[reg] = q;
      }
      if (l31 == 0) {
        #pragma unroll
        for (int reg = 0; reg < 16; ++reg) {
          SCa[w * 32 + ROWP(reg)] = sv[reg];
          SCb[w * 32 + ROWP(reg)] = qv[reg];
        }
      }
      __syncthreads();
      float g0 = ln_g[l * 128 + nb0 + l31],      lb0 = ln_b[l * 128 + nb0 + l31];
      float g1 = ln_g[l * 128 + nb0 + 32 + l31], lb1 = ln_b[l * 128 + nb0 + 32 + l31];
      #pragma unroll
      for (int reg = 0; reg < 16; ++reg) {
        float s = sv[reg] + SCa[(w ^ 1) * 32 + ROWP(reg)];
        float q = qv[reg] + SCb[(w ^ 1) * 32 + ROWP(reg)];
        float mu = s * (1.f / 128.f);
        float var = q * (1.f / 128.f) - mu * mu;
        float inv = 1.f / sqrtf(var + 1e-5f);
        magP[reg]      = g0 * ((accM[0][reg] - mu) * inv) + lb0;
        magP[16 + reg] = g1 * ((accM[1][reg] - mu) * inv) + lb1;
      }
    }
    __syncthreads();                       // AV1 reads of R1 done (all waves past LN barrier)
    stageScatter(R1s, phP, nb0, l31, h5, mblk);      // ph[a][h] -> R1 (over vm)
    __syncthreads();

    // vp = ph @ Wvp (D[a][h]); init bvp[h]
    f32x16 accV[2];
    #pragma unroll
    for (int tl = 0; tl < 2; ++tl) {
      float bv = bvp[l * 128 + nb0 + 32 * tl + l31];
      #pragma unroll
      for (int reg = 0; reg < 16; ++reg) accV[tl][reg] = bv;
    }
    gemmNW(accV, R1s, wvpP, mblk, w1, l31, h5, lane);
    __syncthreads();                       // ph reads done
    stageB64(R1s, accV, nb0, l31, h5, mblk, 1.0f);   // vp[h][a] -> R1
    __syncthreads();

    // new_ph = attn @ vp + ph (init acc = phP)
    f32x16 accP[2];
    #pragma unroll
    for (int tl = 0; tl < 2; ++tl)
      #pragma unroll
      for (int reg = 0; reg < 16; ++reg) accP[tl][reg] = phP[tl * 16 + reg];
    gemmLL(accP, R2s, R1s, mblk, nb0, l31, h5);
    #pragma unroll
    for (int tl = 0; tl < 2; ++tl)
      #pragma unroll
      for (int reg = 0; reg < 16; ++reg) phP[tl * 16 + reg] = accP[tl][reg];
  } // layers

  // ---- real/imag -> RealProjection ----
  float reB[32], imB[32];
  #pragma unroll
  for (int i = 0; i < 32; ++i) {
    float s_, c_;
    __sincosf(phP[i], &s_, &c_);
    reB[i] = magP[i] * c_;
    imB[i] = magP[i] * s_;
  }
  __syncthreads();                         // last AV2 reads done
  stageScatter(R1s, reB, nb0, l31, h5, mblk);
  stageScatter(R2s, imB, nb0, l31, h5, mblk);
  __syncthreads();
  f32x16 accR[2];
  #pragma unroll
  for (int tl = 0; tl < 2; ++tl) {
    float bv = rp_b[nb0 + 32 * tl + l31];
    #pragma unroll
    for (int reg = 0; reg < 16; ++reg) accR[tl][reg] = bv;
  }
  gemmNW(accR, R1s, wpre + (size_t)16 * 65536, mblk, w1, l31, h5, lane);  // real @ rpA
  gemmNW(accR, R2s, wpre + (size_t)17 * 65536, mblk, w1, l31, h5, lane);  // imag @ rpB

  // ---- pooling (column sum over atoms) ----
  #pragma unroll
  for (int tl = 0; tl < 2; ++tl) {
    float ps = 0.f;
    #pragma unroll
    for (int reg = 0; reg < 16; ++reg) ps += accR[tl][reg];
    ps += __shfl_xor(ps, 32);
    if (h5 == 0) SCa[(w >> 1) * 128 + nb0 + 32 * tl + l31] = ps;
  }
  __syncthreads();
  if (t < 128) {
    float cs = SCa[t] + SCa[128 + t] + SCa[256 + t] + SCa[384 + t];
    SCb[t] = cs;
  }
  __syncthreads();
  if (t < 128) {
    float acc = h1_b[t];
    for (int i = 0; i < 128; ++i) {
      float cs = SCb[i];
      acc += cs * (h1_W[(size_t)i * 128 + t] * (1.f / 128.f) +
                   h1_W[(size_t)(128 + i) * 128 + t]);
    }
    float hv = acc / (1.f + __expf(-acc));   // SiLU
    SCb[128 + t] = hv * h2_W[t];
  }
  __syncthreads();
  if (t < 64) {
    float s2 = SCb[128 + t] + SCb[192 + t];
    #pragma unroll
    for (int off = 32; off >= 1; off >>= 1) s2 += __shfl_xor(s2, off);
    if (t == 0) out[b] = s2 + h2_b[0];
  }
}

extern "C" void kernel_launch(void* const* d_in, const int* in_sizes, int n_in,
                              void* d_out, int out_size, void* d_ws, size_t ws_size,
                              hipStream_t stream) {
  const float* atom_types = (const float*)d_in[0];
  const float* coords     = (const float*)d_in[1];
  const int*   edge_index = (const int*)  d_in[2];
  const float* edge_attr  = (const float*)d_in[3];
  const float* emb_Wm = (const float*)d_in[4];
  const float* emb_bm = (const float*)d_in[5];
  const float* emb_Wp = (const float*)d_in[6];
  const float* emb_bp = (const float*)d_in[7];
  const float* Wq  = (const float*)d_in[8];
  const float* bq  = (const float*)d_in[9];
  const float* Wk  = (const float*)d_in[10];
  const float* bk  = (const float*)d_in[11];
  const float* Wvm = (const float*)d_in[12];
  const float* bvm = (const float*)d_in[13];
  const float* Wvp = (const float*)d_in[14];
  const float* bvp = (const float*)d_in[15];
  const float* We  = (const float*)d_in[16];
  const float* be  = (const float*)d_in[17];
  const float* dist_scale = (const float*)d_in[18];
  const float* ln_g = (const float*)d_in[19];
  const float* ln_b = (const float*)d_in[20];
  const float* rp_W = (const float*)d_in[21];
  const float* rp_b = (const float*)d_in[22];
  const float* h1_W = (const float*)d_in[23];
  const float* h1_b = (const float*)d_in[24];
  const float* h2_W = (const float*)d_in[25];
  const float* h2_b = (const float*)d_in[26];
  float* out = (float*)d_out;
  short* wpre = (short*)d_ws;   // 18 matrices * 65536 shorts = 2.36 MB

  hipLaunchKernelGGL(prep_kernel, dim3(72), dim3(512), 0, stream,
                     Wq, Wk, Wvm, Wvp, rp_W, wpre);
  hipLaunchKernelGGL(cpt_kernel, dim3(1024), dim3(512), 0, stream,
                     atom_types, coords, edge_index, edge_attr,
                     emb_Wm, emb_bm, emb_Wp, emb_bp,
                     bq, bk, bvm, bvp,
                     We, be, dist_scale, ln_g, ln_b,
                     rp_b, h1_W, h1_b, h2_W, h2_b,
                     (const short*)wpre, out);
}